// Round 1
// baseline (12130.071 us; speedup 1.0000x reference)
//
#include <hip/hip_runtime.h>

// LSTM: T=512, B=128, D=1024, H=1024. fp32 I/O, bf16 MFMA compute.
// Per-timestep kernel launch (512 nodes in graph). Gates interleaved in N:
// gate-col n = hcol*4 + gate, so f/i/g/o for one cell sit in lanes l^{0,1,2,3}.

#define TT 512
#define BB 128
#define DD 1024
#define HH 1024

typedef __attribute__((ext_vector_type(8))) short short8;
typedef __attribute__((ext_vector_type(4))) float f32x4;

__device__ __forceinline__ unsigned short f2bf(float x) {
    union { float f; unsigned int u; } a; a.f = x;
    unsigned int r = a.u + 0x7fff + ((a.u >> 16) & 1);
    return (unsigned short)(r >> 16);
}

__device__ __forceinline__ float sigmoidf_(float x) {
    return 1.0f / (1.0f + expf(-x));
}

// LDS byte offset with XOR swizzle: row stride 256 B (128 bf16), 16B-slot XOR.
__device__ __forceinline__ unsigned aoff(int row, int k) {
    return (unsigned)(row * 256 + ((k * 2) ^ ((row & 7) << 4)));
}

// ---------------- phase 0: weight fp32->bf16, state zero ----------------

__global__ __launch_bounds__(256) void cvt_w(const float* __restrict__ Wf,
                                             const float* __restrict__ Wi,
                                             const float* __restrict__ Wg,
                                             const float* __restrict__ Wo,
                                             unsigned short* __restrict__ dst) {
    size_t i4 = (size_t)blockIdx.x * 256 + threadIdx.x;  // float4 index
    // per-gate: 1024*2048 = 2097152 elems = 524288 float4
    int g = (int)(i4 >> 19);
    size_t off = (i4 & 524287) * 4;
    const float* src = (g == 0) ? Wf : (g == 1) ? Wi : (g == 2) ? Wg : Wo;
    float4 v = *(const float4*)(src + off);
    unsigned int lo = (unsigned)f2bf(v.x) | ((unsigned)f2bf(v.y) << 16);
    unsigned int hi = (unsigned)f2bf(v.z) | ((unsigned)f2bf(v.w) << 16);
    uint2 u; u.x = lo; u.y = hi;
    *(uint2*)(dst + (size_t)g * 2097152 + off) = u;
}

__global__ __launch_bounds__(256) void zero_ws(unsigned int* __restrict__ p) {
    p[blockIdx.x * 256 + threadIdx.x] = 0u;  // grid sized exactly
}

// ---------------- per-timestep LSTM step ----------------
// grid = 256 blocks: rg = bid>>7 (row half: 64 batch rows), cg = bid&127 (8 h-cols)
// block = 256 threads = 4 waves: wave w -> row-half rh=w>>1 (32 rows), col-tile ct=w&1
// K = 2048 fused (x | h), chunks of 128, double-buffered LDS.

__global__ __launch_bounds__(256) void lstm_step(
    const float* __restrict__ X,            // [T,B,D] fp32
    const unsigned short* __restrict__ Wq,  // [4][1024][2048] bf16
    const float* __restrict__ bfp, const float* __restrict__ bip,
    const float* __restrict__ bgp, const float* __restrict__ bop,
    const unsigned short* __restrict__ h_prev,  // [128][1024] bf16
    unsigned short* __restrict__ h_next,        // [128][1024] bf16
    float* __restrict__ c_ws,                   // [128][1024] fp32
    float* __restrict__ out,                    // outputs | hT | cT
    int t) {
    __shared__ __align__(16) unsigned char smem[49152];
    // A buffers: 0, 16384 (64 rows x 128 k bf16). B buffers: 32768, 40960 (32 x 128).

    const int tid = threadIdx.x;
    const int l = tid & 63;
    const int w = tid >> 6;
    const int rh = w >> 1, ct = w & 1;
    const int rg = blockIdx.x >> 7;
    const int cg = blockIdx.x & 127;

    // lane-fixed epilogue mapping: gate-col n = ct*16 + (l&15); gate = n&3, hcol = n>>2
    const int g0 = l & 3;
    const int hcol = ct * 4 + ((l & 15) >> 2);
    const int j = cg * 8 + hcol;
    const float bfv = bfp[j], biv = bip[j], bgv = bgp[j], bov = bop[j];

    // staging thread mapping
    const int srow = tid >> 2;           // 0..63
    const int sk4 = (tid & 3) * 4;       // x chunk: float4 columns
    const int sk8 = (tid & 3) * 8;       // h chunk: bf16x8 columns
    const int bn = tid >> 3;             // 0..31 B rows (gate-cols)
    const int bk = (tid & 7) * 16;
    const int bgate = bn & 3;
    const int bj = cg * 8 + (bn >> 2);
    const unsigned short* wrow = Wq + ((size_t)(bgate * 1024 + bj)) * 2048;

    const float* xrow = X + ((size_t)t * BB + rg * 64 + srow) * DD;
    const unsigned short* hrow = h_prev + (size_t)(rg * 64 + srow) * HH;

    f32x4 acc0 = {0.f, 0.f, 0.f, 0.f};
    f32x4 acc1 = {0.f, 0.f, 0.f, 0.f};

    float4 xv[8]; short8 hv[4]; short8 bv[2];

    auto load_chunk = [&](int c) {
        const int kb = c * 128;
        if (kb < 1024) {
            const float* p = xrow + kb + sk4;
#pragma unroll
            for (int q = 0; q < 8; ++q) xv[q] = *(const float4*)(p + 16 * q);
        } else {
            const unsigned short* p = hrow + (kb - 1024) + sk8;
#pragma unroll
            for (int q = 0; q < 4; ++q) hv[q] = *(const short8*)(p + 32 * q);
        }
        const unsigned short* wp = wrow + kb + bk;
        bv[0] = *(const short8*)(wp);
        bv[1] = *(const short8*)(wp + 8);
    };

    auto write_chunk = [&](int c) {
        unsigned char* Ab = smem + ((c & 1) ? 16384 : 0);
        unsigned char* Bb = smem + ((c & 1) ? 40960 : 32768);
        const int kb = c * 128;
        if (kb < 1024) {
#pragma unroll
            for (int q = 0; q < 8; ++q) {
                int k = sk4 + 16 * q;
                unsigned int lo = (unsigned)f2bf(xv[q].x) | ((unsigned)f2bf(xv[q].y) << 16);
                unsigned int hi = (unsigned)f2bf(xv[q].z) | ((unsigned)f2bf(xv[q].w) << 16);
                uint2 u; u.x = lo; u.y = hi;
                *(uint2*)(Ab + aoff(srow, k)) = u;
            }
        } else {
#pragma unroll
            for (int q = 0; q < 4; ++q) {
                int k = sk8 + 32 * q;
                *(short8*)(Ab + aoff(srow, k)) = hv[q];
            }
        }
        *(short8*)(Bb + aoff(bn, bk)) = bv[0];
        *(short8*)(Bb + aoff(bn, bk + 8)) = bv[1];
    };

    auto compute_chunk = [&](int c) {
        const unsigned char* Ab = smem + ((c & 1) ? 16384 : 0);
        const unsigned char* Bb = smem + ((c & 1) ? 40960 : 32768);
        const int ar0 = rh * 32 + (l & 15);
        const int bnn = ct * 16 + (l & 15);
#pragma unroll
        for (int ks = 0; ks < 4; ++ks) {
            const int kk = ks * 32 + (l >> 4) * 8;
            short8 a0 = *(const short8*)(Ab + aoff(ar0, kk));
            short8 a1 = *(const short8*)(Ab + aoff(ar0 + 16, kk));
            short8 b = *(const short8*)(Bb + aoff(bnn, kk));
            acc0 = __builtin_amdgcn_mfma_f32_16x16x32_bf16(a0, b, acc0, 0, 0, 0);
            acc1 = __builtin_amdgcn_mfma_f32_16x16x32_bf16(a1, b, acc1, 0, 0, 0);
        }
    };

    load_chunk(0);
    write_chunk(0);
    __syncthreads();

    for (int c = 0; c < 16; ++c) {
        if (c < 15) load_chunk(c + 1);
        compute_chunk(c);
        if (c < 15) write_chunk(c + 1);
        __syncthreads();
    }

    // epilogue: combine gates across lanes l^{1,2,3}, update c/h
    const int rbase = rg * 64 + rh * 32;
#pragma unroll
    for (int rt = 0; rt < 2; ++rt) {
        f32x4 z4 = rt ? acc1 : acc0;
#pragma unroll
        for (int r = 0; r < 4; ++r) {
            float z = z4[r];
            float v1 = __shfl_xor(z, 1);
            float v2 = __shfl_xor(z, 2);
            float v3 = __shfl_xor(z, 3);
            // value for gate gg lives at xor-distance m = g0^gg
            int m;
            m = g0;      float zf = (m == 0) ? z : (m == 1) ? v1 : (m == 2) ? v2 : v3;
            m = g0 ^ 1;  float zi = (m == 0) ? z : (m == 1) ? v1 : (m == 2) ? v2 : v3;
            m = g0 ^ 2;  float zg = (m == 0) ? z : (m == 1) ? v1 : (m == 2) ? v2 : v3;
            m = g0 ^ 3;  float zo = (m == 0) ? z : (m == 1) ? v1 : (m == 2) ? v2 : v3;
            if (g0 == 0) {
                float fg = sigmoidf_(zf + bfv);
                float ig = sigmoidf_(zi + biv);
                float gg = tanhf(zg + bgv);
                float og = sigmoidf_(zo + bov);
                const int row = rbase + rt * 16 + (l >> 4) * 4 + r;
                const size_t idx = (size_t)row * HH + j;
                float cc = fg * c_ws[idx] + ig * gg;
                c_ws[idx] = cc;
                float hh = og * tanhf(cc);
                out[((size_t)t * BB + row) * HH + j] = hh;
                h_next[idx] = f2bf(hh);
                if (t == TT - 1) {
                    out[(size_t)TT * BB * HH + idx] = hh;
                    out[(size_t)TT * BB * HH + (size_t)BB * HH + idx] = cc;
                }
            }
        }
    }
}

// ---------------- host ----------------

extern "C" void kernel_launch(void* const* d_in, const int* in_sizes, int n_in,
                              void* d_out, int out_size, void* d_ws, size_t ws_size,
                              hipStream_t stream) {
    const float* X  = (const float*)d_in[0];
    const float* Wf = (const float*)d_in[1];
    const float* bf = (const float*)d_in[2];
    const float* Wi = (const float*)d_in[3];
    const float* bi = (const float*)d_in[4];
    const float* Wg = (const float*)d_in[5];
    const float* bg = (const float*)d_in[6];
    const float* Wo = (const float*)d_in[7];
    const float* bo = (const float*)d_in[8];

    unsigned char* ws = (unsigned char*)d_ws;
    unsigned short* wsW = (unsigned short*)ws;                       // 16 MiB bf16 weights
    unsigned short* hbuf = (unsigned short*)(ws + 16777216);         // 2 x [128][1024] bf16
    float* c_ws = (float*)(ws + 16777216 + 524288);                  // [128][1024] fp32

    // phase 0: convert weights, zero h/c state (runs every call -> deterministic)
    cvt_w<<<dim3(8192), dim3(256), 0, stream>>>(Wf, Wi, Wg, Wo, wsW);
    zero_ws<<<dim3(1024), dim3(256), 0, stream>>>((unsigned int*)(ws + 16777216));

    for (int t = 0; t < TT; ++t) {
        const unsigned short* hp = hbuf + (size_t)(t & 1) * (BB * HH);
        unsigned short* hn = hbuf + (size_t)((t + 1) & 1) * (BB * HH);
        lstm_step<<<dim3(256), dim3(256), 0, stream>>>(
            X, wsW, bf, bi, bg, bo, hp, hn, c_ws, (float*)d_out, t);
    }
}

// Round 2
// 9582.548 us; speedup vs baseline: 1.2659x; 1.2659x over previous
//
#include <hip/hip_runtime.h>

// LSTM: T=512, B=128, D=1024, H=1024. fp32 I/O, bf16 MFMA compute.
// R2: 512 blocks (4 rg x 128 cg), tile 32 rows x 32 gate-cols, 2 blocks/CU.
// W + h staged via global_load_lds(16B) with pre-swizzled source; x-part
// reg-staged fp32->bf16 with T14 issue-early/write-late split.
// Gate interleave in N: gate-col = hcol*4+gate -> f/i/g/o in lanes l^{0,1,2,3}.

#define TT 512
#define BB 128
#define DD 1024
#define HH 1024

typedef __attribute__((ext_vector_type(8))) short short8;
typedef __attribute__((ext_vector_type(4))) float f32x4;

__device__ __forceinline__ unsigned short f2bf(float x) {
    union { float f; unsigned int u; } a; a.f = x;
    unsigned int r = a.u + 0x7fff + ((a.u >> 16) & 1);
    return (unsigned short)(r >> 16);
}

__device__ __forceinline__ float sigmoidf_(float x) {
    return 1.0f / (1.0f + expf(-x));
}

__device__ __forceinline__ void gll16(const void* g, void* l) {
    __builtin_amdgcn_global_load_lds(
        (const __attribute__((address_space(1))) unsigned int*)g,
        (__attribute__((address_space(3))) unsigned int*)l, 16, 0, 0);
}

// ---------------- phase 0: weight fp32->bf16, state zero ----------------

__global__ __launch_bounds__(256) void cvt_w(const float* __restrict__ Wf,
                                             const float* __restrict__ Wi,
                                             const float* __restrict__ Wg,
                                             const float* __restrict__ Wo,
                                             unsigned short* __restrict__ dst) {
    size_t i4 = (size_t)blockIdx.x * 256 + threadIdx.x;  // float4 index
    int g = (int)(i4 >> 19);                             // 524288 float4 per gate
    size_t off = (i4 & 524287) * 4;
    const float* src = (g == 0) ? Wf : (g == 1) ? Wi : (g == 2) ? Wg : Wo;
    float4 v = *(const float4*)(src + off);
    unsigned int lo = (unsigned)f2bf(v.x) | ((unsigned)f2bf(v.y) << 16);
    unsigned int hi = (unsigned)f2bf(v.z) | ((unsigned)f2bf(v.w) << 16);
    uint2 u; u.x = lo; u.y = hi;
    *(uint2*)(dst + (size_t)g * 2097152 + off) = u;
}

__global__ __launch_bounds__(256) void zero_ws(unsigned int* __restrict__ p) {
    p[blockIdx.x * 256 + threadIdx.x] = 0u;  // grid sized exactly (1 MiB)
}

// ---------------- per-timestep LSTM step ----------------
// grid = 512: rg = bid>>7 (32 batch rows), cg = bid&127 (32 gate-cols)
// block = 256 threads = 4 waves, wave (wr=w>>1, wc=w&1) -> 16x16 output frag
// K = 2048 fused (x | h), 16 chunks of 128, double-buffered LDS (32 KiB).

__global__ __launch_bounds__(256) void lstm_step(
    const float* __restrict__ X,            // [T,B,D] fp32
    const unsigned short* __restrict__ Wq,  // [4][1024][2048] bf16
    const float* __restrict__ bfp, const float* __restrict__ bip,
    const float* __restrict__ bgp, const float* __restrict__ bop,
    const unsigned short* __restrict__ h_prev,  // [128][1024] bf16
    unsigned short* __restrict__ h_next,        // [128][1024] bf16
    float* __restrict__ c_ws,                   // [128][1024] fp32
    float* __restrict__ out,                    // outputs | hT | cT
    int t) {
    __shared__ __align__(16) unsigned char smem[32768];
    // A bufs at 0 / 8192 (32 rows x 128 k bf16, linear, 256 B rows)
    // B bufs at 16384 / 24576

    const int tid = threadIdx.x;
    const int l = tid & 63;
    const int w = tid >> 6;
    const int wr = w >> 1, wc = w & 1;
    const int rg = blockIdx.x >> 7;
    const int cg = blockIdx.x & 127;
    const int lq = l >> 4;   // 0..3
    const int sp = l & 15;   // slot position / frag index

    // epilogue lane mapping: col n = wc*16+sp; gate = n&3 = l&3; hcol = sp>>2
    const int g0 = l & 3;
    const int j = cg * 8 + wc * 4 + (sp >> 2);

    // bias folded into accumulator init (per-lane col's own gate bias)
    const float biasv = (g0 == 0) ? bfp[j] : (g0 == 1) ? bip[j]
                      : (g0 == 2) ? bgp[j] : bop[j];
    f32x4 acc_a = {biasv, biasv, biasv, biasv};
    f32x4 acc_b = {0.f, 0.f, 0.f, 0.f};

    // --- gll source pointers (pre-swizzled: LDS stays linear) ---
    // B rows bn (gate-cols of this block): gate=bn&3, hcol j'=cg*8+(bn>>2)
    const int bn0 = w * 8 + lq, bn1 = bn0 + 4;
    const unsigned short* wsrc0 =
        Wq + ((size_t)((bn0 & 3) * 1024 + cg * 8 + (bn0 >> 2))) * 2048 + (sp ^ (bn0 & 7)) * 8;
    const unsigned short* wsrc1 =
        Wq + ((size_t)((bn1 & 3) * 1024 + cg * 8 + (bn1 >> 2))) * 2048 + (sp ^ (bn1 & 7)) * 8;
    const unsigned short* hsrc0 =
        h_prev + (size_t)(rg * 32 + bn0) * 1024 + (sp ^ (bn0 & 7)) * 8;
    const unsigned short* hsrc1 =
        h_prev + (size_t)(rg * 32 + bn1) * 1024 + (sp ^ (bn1 & 7)) * 8;

    // --- x reg-stage mapping: thread -> row(32) x 2 slots(16) ---
    const int xrow = tid >> 3;
    const int xs = (tid & 7) * 2;
    const float* xsrc = X + ((size_t)t * BB + rg * 32 + xrow) * DD + xs * 8;
    const unsigned xw0 = (unsigned)(xrow * 256 + ((xs * 16) ^ ((xrow & 7) << 4)));
    const unsigned xw1 = (unsigned)(xrow * 256 + (((xs + 1) * 16) ^ ((xrow & 7) << 4)));

    float4 xv0, xv1, xv2, xv3;

    auto load_x = [&](int c) {
        const float* p = xsrc + c * 128;
        xv0 = *(const float4*)(p);
        xv1 = *(const float4*)(p + 4);
        xv2 = *(const float4*)(p + 8);
        xv3 = *(const float4*)(p + 12);
    };
    auto write_x = [&](int buf) {
        unsigned char* Ab = smem + (buf ? 8192 : 0);
        unsigned int a0 = (unsigned)f2bf(xv0.x) | ((unsigned)f2bf(xv0.y) << 16);
        unsigned int a1 = (unsigned)f2bf(xv0.z) | ((unsigned)f2bf(xv0.w) << 16);
        unsigned int a2 = (unsigned)f2bf(xv1.x) | ((unsigned)f2bf(xv1.y) << 16);
        unsigned int a3 = (unsigned)f2bf(xv1.z) | ((unsigned)f2bf(xv1.w) << 16);
        unsigned int b0 = (unsigned)f2bf(xv2.x) | ((unsigned)f2bf(xv2.y) << 16);
        unsigned int b1 = (unsigned)f2bf(xv2.z) | ((unsigned)f2bf(xv2.w) << 16);
        unsigned int b2 = (unsigned)f2bf(xv3.x) | ((unsigned)f2bf(xv3.y) << 16);
        unsigned int b3 = (unsigned)f2bf(xv3.z) | ((unsigned)f2bf(xv3.w) << 16);
        uint4 u0; u0.x = a0; u0.y = a1; u0.z = a2; u0.w = a3;
        uint4 u1; u1.x = b0; u1.y = b1; u1.z = b2; u1.w = b3;
        *(uint4*)(Ab + xw0) = u0;
        *(uint4*)(Ab + xw1) = u1;
    };
    auto stage_B = [&](int c, int buf) {
        unsigned char* Bb = smem + 16384 + (buf ? 8192 : 0);
        const int kb = c * 128;
        gll16(wsrc0 + kb, Bb + (w * 8) * 256);
        gll16(wsrc1 + kb, Bb + (w * 8 + 4) * 256);
    };
    auto stage_Ah = [&](int c, int buf) {
        unsigned char* Ab = smem + (buf ? 8192 : 0);
        const int kh = c * 128 - 1024;
        gll16(hsrc0 + kh, Ab + (w * 8) * 256);
        gll16(hsrc1 + kh, Ab + (w * 8 + 4) * 256);
    };
    auto compute = [&](int buf) {
        const unsigned char* Ab = smem + (buf ? 8192 : 0);
        const unsigned char* Bb = smem + 16384 + (buf ? 8192 : 0);
        const int ar = wr * 16 + sp;
        const int br = wc * 16 + sp;
        const unsigned abase = (unsigned)(ar * 256), axor = (unsigned)((ar & 7) << 4);
        const unsigned bbase = (unsigned)(br * 256), bxor = (unsigned)((br & 7) << 4);
#pragma unroll
        for (int ks = 0; ks < 4; ++ks) {
            const unsigned kk2 = (unsigned)((ks * 32 + lq * 8) * 2);
            short8 a = *(const short8*)(Ab + abase + (kk2 ^ axor));
            short8 b = *(const short8*)(Bb + bbase + (kk2 ^ bxor));
            if (ks & 1) acc_b = __builtin_amdgcn_mfma_f32_16x16x32_bf16(a, b, acc_b, 0, 0, 0);
            else        acc_a = __builtin_amdgcn_mfma_f32_16x16x32_bf16(a, b, acc_a, 0, 0, 0);
        }
    };

    // prologue: chunk 0 (x-part)
    load_x(0);
    stage_B(0, 0);
    write_x(0);
    __syncthreads();

    for (int c = 0; c < 16; ++c) {
        const int buf = c & 1, nbuf = buf ^ 1;
        const int nx = c + 1;
        if (c < 15) {
            if (nx < 8) load_x(nx);          // issue x loads early (T14)
            stage_B(nx, nbuf);
            if (nx >= 8) stage_Ah(nx, nbuf);
        }
        compute(buf);
        if (c < 15 && nx < 8) write_x(nbuf); // convert+write after compute
        __syncthreads();
    }

    // epilogue: gather gates from lanes l^{1,2,3}, update c/h
    f32x4 z4 = acc_a + acc_b;
    const int rbase = rg * 32 + wr * 16 + lq * 4;
#pragma unroll
    for (int r = 0; r < 4; ++r) {
        float z = z4[r];
        float v1 = __shfl_xor(z, 1);
        float v2 = __shfl_xor(z, 2);
        float v3 = __shfl_xor(z, 3);
        if (g0 == 0) {
            float fg = sigmoidf_(z);    // bias already in acc
            float ig = sigmoidf_(v1);
            float gg = tanhf(v2);
            float og = sigmoidf_(v3);
            const int row = rbase + r;
            const size_t idx = (size_t)row * HH + j;
            float cc = fg * c_ws[idx] + ig * gg;
            c_ws[idx] = cc;
            float hh = og * tanhf(cc);
            out[((size_t)t * BB + row) * HH + j] = hh;
            h_next[idx] = f2bf(hh);
            if (t == TT - 1) {
                out[(size_t)TT * BB * HH + idx] = hh;
                out[(size_t)TT * BB * HH + (size_t)BB * HH + idx] = cc;
            }
        }
    }
}

// ---------------- host ----------------

extern "C" void kernel_launch(void* const* d_in, const int* in_sizes, int n_in,
                              void* d_out, int out_size, void* d_ws, size_t ws_size,
                              hipStream_t stream) {
    const float* X  = (const float*)d_in[0];
    const float* Wf = (const float*)d_in[1];
    const float* bf = (const float*)d_in[2];
    const float* Wi = (const float*)d_in[3];
    const float* bi = (const float*)d_in[4];
    const float* Wg = (const float*)d_in[5];
    const float* bg = (const float*)d_in[6];
    const float* Wo = (const float*)d_in[7];
    const float* bo = (const float*)d_in[8];

    unsigned char* ws = (unsigned char*)d_ws;
    unsigned short* wsW = (unsigned short*)ws;                 // 16 MiB bf16 weights
    unsigned short* hbuf = (unsigned short*)(ws + 16777216);   // 2 x [128][1024] bf16
    float* c_ws = (float*)(ws + 16777216 + 524288);            // [128][1024] fp32

    cvt_w<<<dim3(8192), dim3(256), 0, stream>>>(Wf, Wi, Wg, Wo, wsW);
    zero_ws<<<dim3(1024), dim3(256), 0, stream>>>((unsigned int*)(ws + 16777216));

    for (int t = 0; t < TT; ++t) {
        const unsigned short* hp = hbuf + (size_t)(t & 1) * (BB * HH);
        unsigned short* hn = hbuf + (size_t)((t + 1) & 1) * (BB * HH);
        lstm_step<<<dim3(512), dim3(256), 0, stream>>>(
            X, wsW, bf, bi, bg, bo, hp, hn, c_ws, (float*)d_out, t);
    }
}